// Round 1
// baseline (67.117 us; speedup 1.0000x reference)
//
#include <hip/hip_runtime.h>

// ResizeFlow: factor-2 trilinear upsample with periodic (dft) wrap, edge anchor,
// then displacement rescale (*2 per channel; all dims have factor 2).
// Input  flow: (2, 3, 96, 96, 96)  f32
// Output      (2, 3, 192, 192, 192) f32
//
// Exact-weight structure at factor 2 / edge anchor:
//   out[2k]   = 0.25*in[(k-1) mod 96] + 0.75*in[k]
//   out[2k+1] = 0.75*in[k]            + 0.25*in[(k+1) mod 96]
// applied along each of z, y, x (separable == trilinear tensor product),
// finally multiplied by 2.0.

#define ISZ 96
#define OSZ 192
#define XQ  (OSZ / 4)   // 48 float4-quads per output row

__global__ __launch_bounds__(256)
void resize_flow_kernel(const float* __restrict__ in, float* __restrict__ out,
                        int total4) {
    int t = blockIdx.x * blockDim.x + threadIdx.x;
    if (t >= total4) return;

    // decode: t -> (bc, z, y, x4); x fastest
    int x4  = t % XQ;
    int rem = t / XQ;
    int y   = rem % OSZ; rem /= OSZ;
    int z   = rem % OSZ; rem /= OSZ;
    int bc  = rem;                      // 0..5 (batch*channel)

    const float* __restrict__ base = in + (size_t)bc * (ISZ * ISZ * ISZ);

    // per-axis neighbor indices + weights (wrap mod 96)
    int kz = z >> 1;
    int iz0, iz1; float wz0, wz1;
    if ((z & 1) == 0) { iz0 = (kz == 0) ? (ISZ - 1) : (kz - 1); iz1 = kz;
                        wz0 = 0.25f; wz1 = 0.75f; }
    else              { iz0 = kz; iz1 = (kz == ISZ - 1) ? 0 : (kz + 1);
                        wz0 = 0.75f; wz1 = 0.25f; }

    int ky = y >> 1;
    int iy0, iy1; float wy0, wy1;
    if ((y & 1) == 0) { iy0 = (ky == 0) ? (ISZ - 1) : (ky - 1); iy1 = ky;
                        wy0 = 0.25f; wy1 = 0.75f; }
    else              { iy0 = ky; iy1 = (ky == ISZ - 1) ? 0 : (ky + 1);
                        wy0 = 0.75f; wy1 = 0.25f; }

    // input x indices needed for outputs [4*x4 .. 4*x4+3]: xm-1, xm, xm+1, xm+2
    int xm = 2 * x4;
    int xa = (xm == 0) ? (ISZ - 1) : (xm - 1);
    int xd = (xm + 2 == ISZ) ? 0 : (xm + 2);

    float r0 = 0.f, r1 = 0.f, r2 = 0.f, r3 = 0.f;
#define ACC(IZ, IY, W) do {                                             \
        const float* __restrict__ p = base + ((size_t)(IZ) * ISZ + (IY)) * ISZ; \
        float w = (W);                                                  \
        r0 = fmaf(w, p[xa],     r0);                                    \
        r1 = fmaf(w, p[xm],     r1);                                    \
        r2 = fmaf(w, p[xm + 1], r2);                                    \
        r3 = fmaf(w, p[xd],     r3);                                    \
    } while (0)
    ACC(iz0, iy0, wz0 * wy0);
    ACC(iz0, iy1, wz0 * wy1);
    ACC(iz1, iy0, wz1 * wy0);
    ACC(iz1, iy1, wz1 * wy1);
#undef ACC

    const float s = 2.0f;  // displacement rescale osz/isz
    float4 o;
    o.x = s * (0.25f * r0 + 0.75f * r1);
    o.y = s * (0.75f * r1 + 0.25f * r2);
    o.z = s * (0.25f * r1 + 0.75f * r2);
    o.w = s * (0.75f * r2 + 0.25f * r3);

    *reinterpret_cast<float4*>(out + (size_t)t * 4) = o;
}

extern "C" void kernel_launch(void* const* d_in, const int* in_sizes, int n_in,
                              void* d_out, int out_size, void* d_ws, size_t ws_size,
                              hipStream_t stream) {
    const float* in = (const float*)d_in[0];
    float* out = (float*)d_out;

    int total4 = out_size / 4;                  // 10,616,832 threads
    int block = 256;
    int grid = (total4 + block - 1) / block;    // 41,472 blocks

    resize_flow_kernel<<<grid, block, 0, stream>>>(in, out, total4);
}

// Round 2
// 42.102 us; speedup vs baseline: 1.5942x; 1.5942x over previous
//
#include <hip/hip_runtime.h>

// ResizeFlow: factor-2 trilinear upsample, periodic (dft) wrap, edge anchor,
// then displacement rescale ×2 (osz/isz, per channel — all dims factor 2).
// Input  (2,3,96,96,96) f32 -> Output (2,3,192,192,192) f32.
//
// out[2k]   = 0.25*in[(k-1) mod 96] + 0.75*in[k]
// out[2k+1] = 0.75*in[k]            + 0.25*in[(k+1) mod 96]   (each axis)
//
// One thread computes a 2(z) x 2(y) x 4(x) output brick from a
// 3 x 3 x {xa, xm, xm+1, xd} input neighborhood: 27 load instructions
// (9 rows x [float2 center + 2 scalars]) -> 16 outputs, 4 float4 nt-stores.
//
// Chunked XCD swizzle: consecutive blockIdx round-robin across 8 XCDs, so
// remap b -> (b%8)*(nwg/8) + b/8 to give each XCD a contiguous work chunk;
// per-XCD input slab ~2.7 MB < 4 MB L2. Non-temporal stores keep the 166 MB
// write stream from evicting the input out of L2.

#define ISZ  96
#define OSZ  192
#define NX4  48            // output-x quads per row
#define ZSTR (ISZ * ISZ)   // 9216

typedef float vf4 __attribute__((ext_vector_type(4)));

struct Q4 { float a, b, c, d; };   // input row samples at xa, xm, xm+1, xd

__global__ __launch_bounds__(256)
void resize_flow_kernel(const float* __restrict__ in, float* __restrict__ out) {
    // chunked XCD swizzle (gridDim.x = 10368, divisible by 8)
    unsigned bid = blockIdx.x;
    unsigned wid = (bid & 7u) * (gridDim.x >> 3) + (bid >> 3);
    unsigned t   = wid * 256u + threadIdx.x;

    int x4 = (int)(t % NX4);
    unsigned r = t / NX4;
    int ky = (int)(r % ISZ); r /= ISZ;
    int kz = (int)(r % ISZ);
    int bc = (int)(r / ISZ);               // 0..5

    // wrapped neighbor indices
    int kzm = (kz == 0)       ? ISZ - 1 : kz - 1;
    int kzp = (kz == ISZ - 1) ? 0       : kz + 1;
    int kym = (ky == 0)       ? ISZ - 1 : ky - 1;
    int kyp = (ky == ISZ - 1) ? 0       : ky + 1;

    int xm = 2 * x4;
    int xa = (x4 == 0)       ? ISZ - 1 : xm - 1;
    int xd = (x4 == NX4 - 1) ? 0       : xm + 2;

    const float* base = in + (size_t)bc * (ISZ * ZSTR);

    auto ld = [&](const float* row) -> Q4 {
        float2 m = *reinterpret_cast<const float2*>(row + xm);  // 8B aligned
        Q4 q; q.a = row[xa]; q.b = m.x; q.c = m.y; q.d = row[xd];
        return q;
    };

    // y-blend within one z-plane: A = dy0 = 0.25*rm + 0.75*r0,
    //                             B = dy1 = 0.75*r0 + 0.25*rp
    auto yblend = [&](const float* pz, Q4& A, Q4& B) {
        Q4 rm = ld(pz + kym * ISZ);
        Q4 r0 = ld(pz + ky  * ISZ);
        Q4 rp = ld(pz + kyp * ISZ);
        A.a = fmaf(0.25f, rm.a, 0.75f * r0.a);
        A.b = fmaf(0.25f, rm.b, 0.75f * r0.b);
        A.c = fmaf(0.25f, rm.c, 0.75f * r0.c);
        A.d = fmaf(0.25f, rm.d, 0.75f * r0.d);
        B.a = fmaf(0.25f, rp.a, 0.75f * r0.a);
        B.b = fmaf(0.25f, rp.b, 0.75f * r0.b);
        B.c = fmaf(0.25f, rp.c, 0.75f * r0.c);
        B.d = fmaf(0.25f, rp.d, 0.75f * r0.d);
    };

    Q4 Am, Bm, A0, B0, Ap, Bp;
    yblend(base + (size_t)kzm * ZSTR, Am, Bm);
    yblend(base + (size_t)kz  * ZSTR, A0, B0);
    yblend(base + (size_t)kzp * ZSTR, Ap, Bp);

    // z-blend with the ×2 displacement rescale folded in: weights (0.5, 1.5)
    auto zblend = [](float wl, const Q4& L, float wh, const Q4& H) -> Q4 {
        Q4 q;
        q.a = fmaf(wl, L.a, wh * H.a);
        q.b = fmaf(wl, L.b, wh * H.b);
        q.c = fmaf(wl, L.c, wh * H.c);
        q.d = fmaf(wl, L.d, wh * H.d);
        return q;
    };
    Q4 q00 = zblend(0.5f, Am, 1.5f, A0);   // dz=0, dy=0
    Q4 q01 = zblend(0.5f, Bm, 1.5f, B0);   // dz=0, dy=1
    Q4 q10 = zblend(1.5f, A0, 0.5f, Ap);   // dz=1, dy=0
    Q4 q11 = zblend(1.5f, B0, 0.5f, Bp);   // dz=1, dy=1

    // x-blend + non-temporal float4 store
    auto xstore = [&](const Q4& q, int oz, int oy) {
        vf4 o;
        o.x = fmaf(0.25f, q.a, 0.75f * q.b);
        o.y = fmaf(0.25f, q.c, 0.75f * q.b);
        o.z = fmaf(0.25f, q.b, 0.75f * q.c);
        o.w = fmaf(0.25f, q.d, 0.75f * q.c);
        float* p = out + (((size_t)bc * OSZ + oz) * OSZ + oy) * OSZ + 4 * x4;
        __builtin_nontemporal_store(o, reinterpret_cast<vf4*>(p));
    };
    xstore(q00, 2 * kz,     2 * ky);
    xstore(q01, 2 * kz,     2 * ky + 1);
    xstore(q10, 2 * kz + 1, 2 * ky);
    xstore(q11, 2 * kz + 1, 2 * ky + 1);
}

extern "C" void kernel_launch(void* const* d_in, const int* in_sizes, int n_in,
                              void* d_out, int out_size, void* d_ws, size_t ws_size,
                              hipStream_t stream) {
    const float* in = (const float*)d_in[0];
    float* out = (float*)d_out;

    // 6 * 96 * 96 * 48 = 2,654,208 threads; 10,368 blocks (divisible by 8)
    int total = 6 * ISZ * ISZ * NX4;
    int block = 256;
    int grid  = total / block;

    resize_flow_kernel<<<grid, block, 0, stream>>>(in, out);
}

// Round 3
// 36.603 us; speedup vs baseline: 1.8337x; 1.1502x over previous
//
#include <hip/hip_runtime.h>

// ResizeFlow: factor-2 trilinear upsample, periodic (dft) wrap, edge anchor,
// then displacement rescale ×2 (folded into the z-blend weights: 0.5/1.5).
// Input (2,3,96,96,96) f32 -> Output (2,3,192,192,192) f32.
//
// out[2k]   = 0.25*in[(k-1) mod 96] + 0.75*in[k]
// out[2k+1] = 0.75*in[k]            + 0.25*in[(k+1) mod 96]   (each axis)
//
// One thread computes a 4(z) x 4(y) x 4(x) output brick from a
// 4-plane x 4-row x {xa, xm, xm+1, xd} input neighborhood.
// Planes are streamed p0..p3; each output z-quad is stored as soon as its
// two contributing planes are blended, capping live registers at ~16 quads.
// Input row multiplicity drops to 4 (was 9 at 2x2 bricks) -> gather L1
// traffic ~84 MB vs ~570 MB.
//
// Chunked XCD swizzle: per-XCD contiguous work chunk -> input slab ~2.6 MB
// fits the 4 MB per-XCD L2. Non-temporal float4 stores keep the 166 MB
// write stream from evicting the input.

#define ISZ  96
#define OSZ  192
#define NX4  48            // output-x quads per output row
#define NT   48            // brick count per axis (96 input / 2 per brick)
#define ZSTR (ISZ * ISZ)

typedef float vf4 __attribute__((ext_vector_type(4)));

struct Q4 { float a, b, c, d; };   // samples at xa, xm, xm+1, xd

__device__ __forceinline__ Q4 q_wsum(float wl, const Q4& L, float wh, const Q4& H) {
    Q4 q;
    q.a = fmaf(wl, L.a, wh * H.a);
    q.b = fmaf(wl, L.b, wh * H.b);
    q.c = fmaf(wl, L.c, wh * H.c);
    q.d = fmaf(wl, L.d, wh * H.d);
    return q;
}
__device__ __forceinline__ Q4 q_scale(float w, const Q4& Y) {
    Q4 q; q.a = w * Y.a; q.b = w * Y.b; q.c = w * Y.c; q.d = w * Y.d; return q;
}
__device__ __forceinline__ void q_acc(Q4& O, float w, const Q4& Y) {
    O.a = fmaf(w, Y.a, O.a);
    O.b = fmaf(w, Y.b, O.b);
    O.c = fmaf(w, Y.c, O.c);
    O.d = fmaf(w, Y.d, O.d);
}

__global__ __launch_bounds__(256)
void resize_flow_kernel(const float* __restrict__ in, float* __restrict__ out) {
    // chunked XCD swizzle (gridDim.x = 2592, divisible by 8)
    unsigned bid = blockIdx.x;
    unsigned wid = (bid & 7u) * (gridDim.x >> 3) + (bid >> 3);
    unsigned t   = wid * 256u + threadIdx.x;

    int x4 = (int)(t % NX4);
    unsigned r = t / NX4;
    int ty = (int)(r % NT); r /= NT;
    int tz = (int)(r % NT);
    int bc = (int)(r / NT);                 // 0..5

    // input x indices for output quad [4*x4 .. 4*x4+3]
    int xm = 2 * x4;
    int xa = (x4 == 0)       ? ISZ - 1 : xm - 1;
    int xd = (x4 == NX4 - 1) ? 0       : xm + 2;

    // input rows / planes for this brick (wrapped)
    int ky  = 2 * ty;
    int ry0 = (ky == 0) ? ISZ - 1 : ky - 1;
    int ry1 = ky, ry2 = ky + 1;
    int ry3 = (ky + 2 == ISZ) ? 0 : ky + 2;

    int kz  = 2 * tz;
    int pz0 = (kz == 0) ? ISZ - 1 : kz - 1;
    int pz1 = kz, pz2 = kz + 1;
    int pz3 = (kz + 2 == ISZ) ? 0 : kz + 2;

    const float* base = in + (size_t)bc * (ISZ * ZSTR);

    auto ld = [&](const float* row) -> Q4 {
        float2 m = *reinterpret_cast<const float2*>(row + xm);  // 8B aligned
        Q4 q; q.a = row[xa]; q.b = m.x; q.c = m.y; q.d = row[xd];
        return q;
    };

    // load one input plane's 4 rows and y-blend into 4 output-y quads
    auto yblend = [&](int p, Q4& Y0, Q4& Y1, Q4& Y2, Q4& Y3) {
        const float* pp = base + (size_t)p * ZSTR;
        Q4 R0 = ld(pp + ry0 * ISZ);
        Q4 R1 = ld(pp + ry1 * ISZ);
        Q4 R2 = ld(pp + ry2 * ISZ);
        Q4 R3 = ld(pp + ry3 * ISZ);
        Y0 = q_wsum(0.25f, R0, 0.75f, R1);   // oy = 4ty
        Y1 = q_wsum(0.75f, R1, 0.25f, R2);   // oy+1
        Y2 = q_wsum(0.25f, R1, 0.75f, R2);   // oy+2
        Y3 = q_wsum(0.75f, R2, 0.25f, R3);   // oy+3
    };

    // x-blend + non-temporal float4 store
    int oyb = 4 * ty, ozb = 4 * tz;
    auto xstore = [&](const Q4& q, int dz, int dy) {
        vf4 o;
        o.x = fmaf(0.25f, q.a, 0.75f * q.b);
        o.y = fmaf(0.75f, q.b, 0.25f * q.c);
        o.z = fmaf(0.25f, q.b, 0.75f * q.c);
        o.w = fmaf(0.75f, q.c, 0.25f * q.d);
        float* p = out + (((size_t)bc * OSZ + (ozb + dz)) * OSZ + (oyb + dy)) * OSZ + 4 * x4;
        __builtin_nontemporal_store(o, reinterpret_cast<vf4*>(p));
    };

    // z-blend weights with the ×2 displacement rescale folded in:
    //   oz = 4tz   : 0.5*P(pz0) + 1.5*P(pz1)
    //   oz+1       : 1.5*P(pz1) + 0.5*P(pz2)
    //   oz+2       : 0.5*P(pz1) + 1.5*P(pz2)
    //   oz+3       : 1.5*P(pz2) + 0.5*P(pz3)
    Q4 Y0, Y1, Y2, Y3;

    // plane p0 -> start dz=0
    yblend(pz0, Y0, Y1, Y2, Y3);
    Q4 A0 = q_scale(0.5f, Y0), A1 = q_scale(0.5f, Y1),
       A2 = q_scale(0.5f, Y2), A3 = q_scale(0.5f, Y3);

    // plane p1 -> finish dz=0; start dz=1, dz=2
    yblend(pz1, Y0, Y1, Y2, Y3);
    q_acc(A0, 1.5f, Y0); q_acc(A1, 1.5f, Y1);
    q_acc(A2, 1.5f, Y2); q_acc(A3, 1.5f, Y3);
    xstore(A0, 0, 0); xstore(A1, 0, 1); xstore(A2, 0, 2); xstore(A3, 0, 3);
    Q4 B0 = q_scale(1.5f, Y0), B1 = q_scale(1.5f, Y1),
       B2 = q_scale(1.5f, Y2), B3 = q_scale(1.5f, Y3);
    Q4 C0 = q_scale(0.5f, Y0), C1 = q_scale(0.5f, Y1),
       C2 = q_scale(0.5f, Y2), C3 = q_scale(0.5f, Y3);

    // plane p2 -> finish dz=1, dz=2; start dz=3
    yblend(pz2, Y0, Y1, Y2, Y3);
    q_acc(B0, 0.5f, Y0); q_acc(B1, 0.5f, Y1);
    q_acc(B2, 0.5f, Y2); q_acc(B3, 0.5f, Y3);
    xstore(B0, 1, 0); xstore(B1, 1, 1); xstore(B2, 1, 2); xstore(B3, 1, 3);
    q_acc(C0, 1.5f, Y0); q_acc(C1, 1.5f, Y1);
    q_acc(C2, 1.5f, Y2); q_acc(C3, 1.5f, Y3);
    xstore(C0, 2, 0); xstore(C1, 2, 1); xstore(C2, 2, 2); xstore(C3, 2, 3);
    Q4 D0 = q_scale(1.5f, Y0), D1 = q_scale(1.5f, Y1),
       D2 = q_scale(1.5f, Y2), D3 = q_scale(1.5f, Y3);

    // plane p3 -> finish dz=3
    yblend(pz3, Y0, Y1, Y2, Y3);
    q_acc(D0, 0.5f, Y0); q_acc(D1, 0.5f, Y1);
    q_acc(D2, 0.5f, Y2); q_acc(D3, 0.5f, Y3);
    xstore(D0, 3, 0); xstore(D1, 3, 1); xstore(D2, 3, 2); xstore(D3, 3, 3);
}

extern "C" void kernel_launch(void* const* d_in, const int* in_sizes, int n_in,
                              void* d_out, int out_size, void* d_ws, size_t ws_size,
                              hipStream_t stream) {
    const float* in = (const float*)d_in[0];
    float* out = (float*)d_out;

    // 6 * 48 * 48 * 48 = 663,552 threads; 2,592 blocks (divisible by 8)
    int total = 6 * NT * NT * NX4;
    int block = 256;
    int grid  = total / block;

    resize_flow_kernel<<<grid, block, 0, stream>>>(in, out);
}

// Round 4
// 36.217 us; speedup vs baseline: 1.8532x; 1.0106x over previous
//
#include <hip/hip_runtime.h>

// ResizeFlow: factor-2 trilinear upsample, periodic (dft) wrap, edge anchor,
// then displacement rescale ×2 (folded into z-blend weights: 0.5/1.5).
// Input (2,3,96,96,96) f32 -> Output (2,3,192,192,192) f32.
//
// out[2k]   = 0.25*in[(k-1) mod 96] + 0.75*in[k]
// out[2k+1] = 0.75*in[k]            + 0.25*in[(k+1) mod 96]   (each axis)
//
// One thread computes a 4(z) x 4(y) x 4(x) output brick from a
// 4-plane x 4-row x {xa, xm, xm+1, xd} input neighborhood (48 load instrs
// per 64 outputs). Planes are streamed with one-plane-ahead prefetch:
// plane p(i+1)'s 12 loads issue before plane p(i) is blended -> 2 planes of
// loads in flight per wave. Outputs store as soon as their 2-plane z-blend
// completes (4 float4 nt stores per output z).
//
// block=64 (1 wave) -> 10368 blocks: fine scheduling quanta (~40 blocks/CU)
// to kill the tail; chunked XCD swizzle keeps each XCD's input slab ~2.6 MB
// inside its 4 MB L2; nt stores keep the 166 MB write stream from evicting
// the input.

#define ISZ  96
#define OSZ  192
#define NX4  48            // output-x quads per output row
#define NT   48            // bricks per axis (96 input / 2 per brick)
#define ZSTR (ISZ * ISZ)

typedef float vf4 __attribute__((ext_vector_type(4)));

struct Q4 { float a, b, c, d; };          // samples at xa, xm, xm+1, xd
struct PL { Q4 r0, r1, r2, r3; };         // one input plane's 4 rows

__device__ __forceinline__ Q4 q_wsum(float wl, const Q4& L, float wh, const Q4& H) {
    Q4 q;
    q.a = fmaf(wl, L.a, wh * H.a);
    q.b = fmaf(wl, L.b, wh * H.b);
    q.c = fmaf(wl, L.c, wh * H.c);
    q.d = fmaf(wl, L.d, wh * H.d);
    return q;
}
__device__ __forceinline__ Q4 q_scale(float w, const Q4& Y) {
    Q4 q; q.a = w * Y.a; q.b = w * Y.b; q.c = w * Y.c; q.d = w * Y.d; return q;
}
__device__ __forceinline__ void q_acc(Q4& O, float w, const Q4& Y) {
    O.a = fmaf(w, Y.a, O.a);
    O.b = fmaf(w, Y.b, O.b);
    O.c = fmaf(w, Y.c, O.c);
    O.d = fmaf(w, Y.d, O.d);
}

__global__ __launch_bounds__(64)
void resize_flow_kernel(const float* __restrict__ in, float* __restrict__ out) {
    // chunked XCD swizzle (gridDim.x = 10368, divisible by 8)
    unsigned bid = blockIdx.x;
    unsigned wid = (bid & 7u) * (gridDim.x >> 3) + (bid >> 3);
    unsigned t   = wid * 64u + threadIdx.x;

    int x4 = (int)(t % NX4);
    unsigned r = t / NX4;
    int ty = (int)(r % NT); r /= NT;
    int tz = (int)(r % NT);
    int bc = (int)(r / NT);                 // 0..5

    // input x indices for output quad [4*x4 .. 4*x4+3]
    int xm = 2 * x4;
    int xa = (x4 == 0)       ? ISZ - 1 : xm - 1;
    int xd = (x4 == NX4 - 1) ? 0       : xm + 2;

    // input rows / planes for this brick (wrapped)
    int ky  = 2 * ty;
    int ry0 = (ky == 0) ? ISZ - 1 : ky - 1;
    int ry1 = ky, ry2 = ky + 1;
    int ry3 = (ky + 2 == ISZ) ? 0 : ky + 2;

    int kz  = 2 * tz;
    int pz0 = (kz == 0) ? ISZ - 1 : kz - 1;
    int pz1 = kz, pz2 = kz + 1;
    int pz3 = (kz + 2 == ISZ) ? 0 : kz + 2;

    const float* base = in + (size_t)bc * (ISZ * ZSTR);

    auto ld = [&](const float* row) -> Q4 {
        float2 m = *reinterpret_cast<const float2*>(row + xm);  // 8B aligned
        Q4 q; q.a = row[xa]; q.b = m.x; q.c = m.y; q.d = row[xd];
        return q;
    };
    auto load_plane = [&](int p) -> PL {
        const float* pp = base + (size_t)p * ZSTR;
        PL L;
        L.r0 = ld(pp + ry0 * ISZ);
        L.r1 = ld(pp + ry1 * ISZ);
        L.r2 = ld(pp + ry2 * ISZ);
        L.r3 = ld(pp + ry3 * ISZ);
        return L;
    };
    // y-blend one plane's rows into 4 output-y quads
    auto yblend = [&](const PL& L, Q4& Y0, Q4& Y1, Q4& Y2, Q4& Y3) {
        Y0 = q_wsum(0.25f, L.r0, 0.75f, L.r1);   // oy = 4ty
        Y1 = q_wsum(0.75f, L.r1, 0.25f, L.r2);   // oy+1
        Y2 = q_wsum(0.25f, L.r1, 0.75f, L.r2);   // oy+2
        Y3 = q_wsum(0.75f, L.r2, 0.25f, L.r3);   // oy+3
    };

    int oyb = 4 * ty, ozb = 4 * tz;
    auto xstore = [&](const Q4& q, int dz, int dy) {
        vf4 o;
        o.x = fmaf(0.25f, q.a, 0.75f * q.b);
        o.y = fmaf(0.75f, q.b, 0.25f * q.c);
        o.z = fmaf(0.25f, q.b, 0.75f * q.c);
        o.w = fmaf(0.75f, q.c, 0.25f * q.d);
        float* p = out + (((size_t)bc * OSZ + (ozb + dz)) * OSZ + (oyb + dy)) * OSZ + 4 * x4;
        __builtin_nontemporal_store(o, reinterpret_cast<vf4*>(p));
    };

    // z-blend weights with the ×2 displacement rescale folded in:
    //   oz = 4tz : 0.5*P(pz0) + 1.5*P(pz1)
    //   oz+1     : 1.5*P(pz1) + 0.5*P(pz2)
    //   oz+2     : 0.5*P(pz1) + 1.5*P(pz2)
    //   oz+3     : 1.5*P(pz2) + 0.5*P(pz3)
    Q4 Y0, Y1, Y2, Y3;

    PL L0 = load_plane(pz0);
    PL L1 = load_plane(pz1);               // prefetch p1 before blending p0

    yblend(L0, Y0, Y1, Y2, Y3);
    Q4 A0 = q_scale(0.5f, Y0), A1 = q_scale(0.5f, Y1),
       A2 = q_scale(0.5f, Y2), A3 = q_scale(0.5f, Y3);

    PL L2 = load_plane(pz2);               // prefetch p2 before blending p1

    yblend(L1, Y0, Y1, Y2, Y3);
    q_acc(A0, 1.5f, Y0); q_acc(A1, 1.5f, Y1);
    q_acc(A2, 1.5f, Y2); q_acc(A3, 1.5f, Y3);
    xstore(A0, 0, 0); xstore(A1, 0, 1); xstore(A2, 0, 2); xstore(A3, 0, 3);
    Q4 B0 = q_scale(1.5f, Y0), B1 = q_scale(1.5f, Y1),
       B2 = q_scale(1.5f, Y2), B3 = q_scale(1.5f, Y3);
    Q4 C0 = q_scale(0.5f, Y0), C1 = q_scale(0.5f, Y1),
       C2 = q_scale(0.5f, Y2), C3 = q_scale(0.5f, Y3);

    PL L3 = load_plane(pz3);               // prefetch p3 before blending p2

    yblend(L2, Y0, Y1, Y2, Y3);
    q_acc(B0, 0.5f, Y0); q_acc(B1, 0.5f, Y1);
    q_acc(B2, 0.5f, Y2); q_acc(B3, 0.5f, Y3);
    xstore(B0, 1, 0); xstore(B1, 1, 1); xstore(B2, 1, 2); xstore(B3, 1, 3);
    q_acc(C0, 1.5f, Y0); q_acc(C1, 1.5f, Y1);
    q_acc(C2, 1.5f, Y2); q_acc(C3, 1.5f, Y3);
    xstore(C0, 2, 0); xstore(C1, 2, 1); xstore(C2, 2, 2); xstore(C3, 2, 3);
    Q4 D0 = q_scale(1.5f, Y0), D1 = q_scale(1.5f, Y1),
       D2 = q_scale(1.5f, Y2), D3 = q_scale(1.5f, Y3);

    yblend(L3, Y0, Y1, Y2, Y3);
    q_acc(D0, 0.5f, Y0); q_acc(D1, 0.5f, Y1);
    q_acc(D2, 0.5f, Y2); q_acc(D3, 0.5f, Y3);
    xstore(D0, 3, 0); xstore(D1, 3, 1); xstore(D2, 3, 2); xstore(D3, 3, 3);
}

extern "C" void kernel_launch(void* const* d_in, const int* in_sizes, int n_in,
                              void* d_out, int out_size, void* d_ws, size_t ws_size,
                              hipStream_t stream) {
    const float* in = (const float*)d_in[0];
    float* out = (float*)d_out;

    // 6 * 48 * 48 * 48 = 663,552 threads; 10,368 one-wave blocks (div by 8)
    int total = 6 * NT * NT * NX4;
    int block = 64;
    int grid  = total / block;

    resize_flow_kernel<<<grid, block, 0, stream>>>(in, out);
}

// Round 5
// 34.354 us; speedup vs baseline: 1.9537x; 1.0542x over previous
//
#include <hip/hip_runtime.h>

// ResizeFlow: factor-2 trilinear upsample, periodic (dft) wrap, edge anchor,
// then displacement rescale ×2 (folded into z-blend weights: 0.5/1.5).
// Input (2,3,96,96,96) f32 -> Output (2,3,192,192,192) f32.
//
// out[2k]   = 0.25*in[(k-1) mod 96] + 0.75*in[k]
// out[2k+1] = 0.75*in[k]            + 0.25*in[(k+1) mod 96]   (each axis)
//
// One thread computes a 4(z) x 4(y) x 4(x) output brick from a
// 4-plane x 4-row x {xa, xm, xm+1, xd} input neighborhood (48 load instrs
// per 64 outputs), planes streamed with one-plane-ahead prefetch.
//
// R5 single-variable change vs R4: REGULAR float4 stores instead of
// __builtin_nontemporal_store. The 7 TB/s fillBuffer reference uses plain
// stores; nt's input-protection rationale is moot (evicted input re-reads
// hit the 256 MB L3, not HBM). Everything else identical: block=64,
// chunked XCD swizzle (input slab ~2.6 MB per XCD L2), 4x4x4 bricks.

#define ISZ  96
#define OSZ  192
#define NX4  48            // output-x quads per output row
#define NT   48            // bricks per axis (96 input / 2 per brick)
#define ZSTR (ISZ * ISZ)

typedef float vf4 __attribute__((ext_vector_type(4)));

struct Q4 { float a, b, c, d; };          // samples at xa, xm, xm+1, xd
struct PL { Q4 r0, r1, r2, r3; };         // one input plane's 4 rows

__device__ __forceinline__ Q4 q_wsum(float wl, const Q4& L, float wh, const Q4& H) {
    Q4 q;
    q.a = fmaf(wl, L.a, wh * H.a);
    q.b = fmaf(wl, L.b, wh * H.b);
    q.c = fmaf(wl, L.c, wh * H.c);
    q.d = fmaf(wl, L.d, wh * H.d);
    return q;
}
__device__ __forceinline__ Q4 q_scale(float w, const Q4& Y) {
    Q4 q; q.a = w * Y.a; q.b = w * Y.b; q.c = w * Y.c; q.d = w * Y.d; return q;
}
__device__ __forceinline__ void q_acc(Q4& O, float w, const Q4& Y) {
    O.a = fmaf(w, Y.a, O.a);
    O.b = fmaf(w, Y.b, O.b);
    O.c = fmaf(w, Y.c, O.c);
    O.d = fmaf(w, Y.d, O.d);
}

__global__ __launch_bounds__(64)
void resize_flow_kernel(const float* __restrict__ in, float* __restrict__ out) {
    // chunked XCD swizzle (gridDim.x = 10368, divisible by 8)
    unsigned bid = blockIdx.x;
    unsigned wid = (bid & 7u) * (gridDim.x >> 3) + (bid >> 3);
    unsigned t   = wid * 64u + threadIdx.x;

    int x4 = (int)(t % NX4);
    unsigned r = t / NX4;
    int ty = (int)(r % NT); r /= NT;
    int tz = (int)(r % NT);
    int bc = (int)(r / NT);                 // 0..5

    // input x indices for output quad [4*x4 .. 4*x4+3]
    int xm = 2 * x4;
    int xa = (x4 == 0)       ? ISZ - 1 : xm - 1;
    int xd = (x4 == NX4 - 1) ? 0       : xm + 2;

    // input rows / planes for this brick (wrapped)
    int ky  = 2 * ty;
    int ry0 = (ky == 0) ? ISZ - 1 : ky - 1;
    int ry1 = ky, ry2 = ky + 1;
    int ry3 = (ky + 2 == ISZ) ? 0 : ky + 2;

    int kz  = 2 * tz;
    int pz0 = (kz == 0) ? ISZ - 1 : kz - 1;
    int pz1 = kz, pz2 = kz + 1;
    int pz3 = (kz + 2 == ISZ) ? 0 : kz + 2;

    const float* base = in + (size_t)bc * (ISZ * ZSTR);

    auto ld = [&](const float* row) -> Q4 {
        float2 m = *reinterpret_cast<const float2*>(row + xm);  // 8B aligned
        Q4 q; q.a = row[xa]; q.b = m.x; q.c = m.y; q.d = row[xd];
        return q;
    };
    auto load_plane = [&](int p) -> PL {
        const float* pp = base + (size_t)p * ZSTR;
        PL L;
        L.r0 = ld(pp + ry0 * ISZ);
        L.r1 = ld(pp + ry1 * ISZ);
        L.r2 = ld(pp + ry2 * ISZ);
        L.r3 = ld(pp + ry3 * ISZ);
        return L;
    };
    // y-blend one plane's rows into 4 output-y quads
    auto yblend = [&](const PL& L, Q4& Y0, Q4& Y1, Q4& Y2, Q4& Y3) {
        Y0 = q_wsum(0.25f, L.r0, 0.75f, L.r1);   // oy = 4ty
        Y1 = q_wsum(0.75f, L.r1, 0.25f, L.r2);   // oy+1
        Y2 = q_wsum(0.25f, L.r1, 0.75f, L.r2);   // oy+2
        Y3 = q_wsum(0.75f, L.r2, 0.25f, L.r3);   // oy+3
    };

    int oyb = 4 * ty, ozb = 4 * tz;
    auto xstore = [&](const Q4& q, int dz, int dy) {
        vf4 o;
        o.x = fmaf(0.25f, q.a, 0.75f * q.b);
        o.y = fmaf(0.75f, q.b, 0.25f * q.c);
        o.z = fmaf(0.25f, q.b, 0.75f * q.c);
        o.w = fmaf(0.75f, q.c, 0.25f * q.d);
        float* p = out + (((size_t)bc * OSZ + (ozb + dz)) * OSZ + (oyb + dy)) * OSZ + 4 * x4;
        *reinterpret_cast<vf4*>(p) = o;          // plain store (R5 change)
    };

    // z-blend weights with the ×2 displacement rescale folded in:
    //   oz = 4tz : 0.5*P(pz0) + 1.5*P(pz1)
    //   oz+1     : 1.5*P(pz1) + 0.5*P(pz2)
    //   oz+2     : 0.5*P(pz1) + 1.5*P(pz2)
    //   oz+3     : 1.5*P(pz2) + 0.5*P(pz3)
    Q4 Y0, Y1, Y2, Y3;

    PL L0 = load_plane(pz0);
    PL L1 = load_plane(pz1);               // prefetch p1 before blending p0

    yblend(L0, Y0, Y1, Y2, Y3);
    Q4 A0 = q_scale(0.5f, Y0), A1 = q_scale(0.5f, Y1),
       A2 = q_scale(0.5f, Y2), A3 = q_scale(0.5f, Y3);

    PL L2 = load_plane(pz2);               // prefetch p2 before blending p1

    yblend(L1, Y0, Y1, Y2, Y3);
    q_acc(A0, 1.5f, Y0); q_acc(A1, 1.5f, Y1);
    q_acc(A2, 1.5f, Y2); q_acc(A3, 1.5f, Y3);
    xstore(A0, 0, 0); xstore(A1, 0, 1); xstore(A2, 0, 2); xstore(A3, 0, 3);
    Q4 B0 = q_scale(1.5f, Y0), B1 = q_scale(1.5f, Y1),
       B2 = q_scale(1.5f, Y2), B3 = q_scale(1.5f, Y3);
    Q4 C0 = q_scale(0.5f, Y0), C1 = q_scale(0.5f, Y1),
       C2 = q_scale(0.5f, Y2), C3 = q_scale(0.5f, Y3);

    PL L3 = load_plane(pz3);               // prefetch p3 before blending p2

    yblend(L2, Y0, Y1, Y2, Y3);
    q_acc(B0, 0.5f, Y0); q_acc(B1, 0.5f, Y1);
    q_acc(B2, 0.5f, Y2); q_acc(B3, 0.5f, Y3);
    xstore(B0, 1, 0); xstore(B1, 1, 1); xstore(B2, 1, 2); xstore(B3, 1, 3);
    q_acc(C0, 1.5f, Y0); q_acc(C1, 1.5f, Y1);
    q_acc(C2, 1.5f, Y2); q_acc(C3, 1.5f, Y3);
    xstore(C0, 2, 0); xstore(C1, 2, 1); xstore(C2, 2, 2); xstore(C3, 2, 3);
    Q4 D0 = q_scale(1.5f, Y0), D1 = q_scale(1.5f, Y1),
       D2 = q_scale(1.5f, Y2), D3 = q_scale(1.5f, Y3);

    yblend(L3, Y0, Y1, Y2, Y3);
    q_acc(D0, 0.5f, Y0); q_acc(D1, 0.5f, Y1);
    q_acc(D2, 0.5f, Y2); q_acc(D3, 0.5f, Y3);
    xstore(D0, 3, 0); xstore(D1, 3, 1); xstore(D2, 3, 2); xstore(D3, 3, 3);
}

extern "C" void kernel_launch(void* const* d_in, const int* in_sizes, int n_in,
                              void* d_out, int out_size, void* d_ws, size_t ws_size,
                              hipStream_t stream) {
    const float* in = (const float*)d_in[0];
    float* out = (float*)d_out;

    // 6 * 48 * 48 * 48 = 663,552 threads; 10,368 one-wave blocks (div by 8)
    int total = 6 * NT * NT * NX4;
    int block = 64;
    int grid  = total / block;

    resize_flow_kernel<<<grid, block, 0, stream>>>(in, out);
}